// Round 1
// baseline (312.100 us; speedup 1.0000x reference)
//
#include <hip/hip_runtime.h>
#include <hip/hip_bf16.h>
#include <stdint.h>
#include <stddef.h>

typedef __bf16 bf16_t;
typedef __bf16 bf16x8 __attribute__((ext_vector_type(8)));
typedef __bf16 bf16x4 __attribute__((ext_vector_type(4)));
typedef float  f32x4  __attribute__((ext_vector_type(4)));

static __device__ __forceinline__ f32x4 mfma16x16x32(bf16x8 a, bf16x8 b, f32x4 c) {
  return __builtin_amdgcn_mfma_f32_16x16x32_bf16(a, b, c, 0, 0, 0);
}

static __device__ __forceinline__ void gld_lds16(const void* g, void* l) {
  __builtin_amdgcn_global_load_lds(
      (const __attribute__((address_space(1))) unsigned int*)g,
      (__attribute__((address_space(3))) unsigned int*)l, 16, 0, 0);
}

// ---------------------------------------------------------------- cvt f32->bf16
__global__ __launch_bounds__(256) void cvt_bf16(const float* __restrict__ in,
                                                bf16_t* __restrict__ out, int n) {
  int stride = gridDim.x * blockDim.x;
  for (int i = blockIdx.x * blockDim.x + threadIdx.x; i * 4 < n; i += stride) {
    float4 v = *(const float4*)(in + (size_t)i * 4);
    bf16x4 o;
    o[0] = (bf16_t)v.x; o[1] = (bf16_t)v.y; o[2] = (bf16_t)v.z; o[3] = (bf16_t)v.w;
    *(bf16x4*)(out + (size_t)i * 4) = o;
  }
}

// ---------------------------------------------------------------- fused weights
// B1t[(qk*1024 + h*128 + f)*1024 + k] = sum_c w_qkv[(qk*1024+h*128+c)*1024+k] * proj[h][c][f]
// grid: 256 blocks = 16 (qk,h) combos * 16 k-tiles(64); 256 threads = 64 k * 4 f-groups
__global__ __launch_bounds__(256) void fuse_w(const float* __restrict__ wqkv,
                                              const float* __restrict__ proj,
                                              bf16_t* __restrict__ B1t) {
  const int blk    = blockIdx.x;
  const int combo  = blk >> 4;       // qk*8 + h
  const int kt     = blk & 15;
  const int qk     = combo >> 3;
  const int h      = combo & 7;
  const int klocal = threadIdx.x & 63;
  const int fg     = threadIdx.x >> 6;  // 0..3
  const int k      = kt * 64 + klocal;

  const float* wbase = wqkv + ((size_t)(qk * 1024 + h * 128)) * 1024 + k;
  const float* pbase = proj + (size_t)h * 16384 + fg * 32;

  float acc[32];
#pragma unroll
  for (int i = 0; i < 32; ++i) acc[i] = 0.f;

  for (int c = 0; c < 128; ++c) {
    float a = wbase[(size_t)c * 1024];
    const float4* p = (const float4*)(pbase + (size_t)c * 128);
#pragma unroll
    for (int i = 0; i < 8; ++i) {
      float4 pv = p[i];
      acc[i * 4 + 0] += a * pv.x;
      acc[i * 4 + 1] += a * pv.y;
      acc[i * 4 + 2] += a * pv.z;
      acc[i * 4 + 3] += a * pv.w;
    }
  }
  bf16_t* obase = B1t + ((size_t)(qk * 1024 + h * 128 + fg * 32)) * 1024 + k;
#pragma unroll
  for (int i = 0; i < 32; ++i) obase[(size_t)i * 1024] = (bf16_t)acc[i];
}

// ---------------------------------------------------------------- main GEMM (m97-style)
// C[M][N] = A[M][K] * Bt[N][K]^T ; A,Bt bf16. EPI: 1 = bf16 out, elu+1 for n<elu_n; 2 = f32 out + bias
#define BM 128
#define BN 128
#define BKG 32

template <int EPI>
__global__ __launch_bounds__(256) void gemm_bt(const bf16_t* __restrict__ A,
                                               const bf16_t* __restrict__ Bt,
                                               void* __restrict__ Cout,
                                               const float* __restrict__ bias,
                                               int M, int N, int K, int elu_n) {
  __shared__ __align__(16) bf16_t As[2][BM * BKG];
  __shared__ __align__(16) bf16_t Bs[2][BN * BKG];
  const int tid  = threadIdx.x;
  const int lane = tid & 63;
  const int wave = tid >> 6;
  const int m0 = blockIdx.y * BM;
  const int n0 = blockIdx.x * BN;
  const int NT = K >> 5;

  const int srow = tid >> 2;          // 0..63
  const int scol = (tid & 3) << 3;    // bf16 elems within row
  const bf16_t* Ag = A  + (size_t)(m0 + srow) * K + scol;
  const bf16_t* Bg = Bt + (size_t)(n0 + srow) * K + scol;
  const size_t rowskip = (size_t)64 * K;

  f32x4 acc[4][4] = {};

  const int mq = (wave >> 1) << 6;
  const int nq = (wave & 1) << 6;
  const int lr = lane & 15;
  const int lk = (lane >> 4) << 3;

  // prologue: stage tile 0
  gld_lds16(Ag,            &As[0][tid * 8]);
  gld_lds16(Ag + rowskip,  &As[0][tid * 8 + 2048]);
  gld_lds16(Bg,            &Bs[0][tid * 8]);
  gld_lds16(Bg + rowskip,  &Bs[0][tid * 8 + 2048]);

  for (int kt = 0; kt < NT; ++kt) {
    const int cur = kt & 1;
    if (kt + 1 < NT) {
      const int k0 = (kt + 1) << 5;
      gld_lds16(Ag + k0,           &As[cur ^ 1][tid * 8]);
      gld_lds16(Ag + rowskip + k0, &As[cur ^ 1][tid * 8 + 2048]);
      gld_lds16(Bg + k0,           &Bs[cur ^ 1][tid * 8]);
      gld_lds16(Bg + rowskip + k0, &Bs[cur ^ 1][tid * 8 + 2048]);
    }
    __syncthreads();
    const bf16_t* as = As[cur];
    const bf16_t* bs = Bs[cur];
    bf16x8 af[4], bfr[4];
#pragma unroll
    for (int t = 0; t < 4; ++t)
      af[t] = *(const bf16x8*)(as + (mq + t * 16 + lr) * BKG + lk);
#pragma unroll
    for (int t = 0; t < 4; ++t)
      bfr[t] = *(const bf16x8*)(bs + (nq + t * 16 + lr) * BKG + lk);
#pragma unroll
    for (int i = 0; i < 4; ++i)
#pragma unroll
      for (int j = 0; j < 4; ++j)
        acc[i][j] = mfma16x16x32(af[i], bfr[j], acc[i][j]);
    __syncthreads();
  }

  // epilogue: C[m][n], col=lane&15, row=(lane>>4)*4+r
  const int r0 = (lane >> 4) << 2;
#pragma unroll
  for (int i = 0; i < 4; ++i) {
#pragma unroll
    for (int j = 0; j < 4; ++j) {
      const int n = n0 + nq + j * 16 + lr;
#pragma unroll
      for (int r = 0; r < 4; ++r) {
        const int m = m0 + mq + i * 16 + r0 + r;
        float v = acc[i][j][r];
        if constexpr (EPI == 1) {
          if (n < elu_n) v = (v > 0.f) ? (v + 1.f) : __expf(v);
          ((bf16_t*)Cout)[(size_t)m * N + n] = (bf16_t)v;
        } else {
          ((float*)Cout)[(size_t)m * N + n] = v + bias[n];
        }
      }
    }
  }
}

// ---------------------------------------------------------------- block attention
// one block per (b,h,c): qp,kp,v are 32x128 tiles inside QKVP (16384 x 3072, cols: qp|kp|v)
__global__ __launch_bounds__(256) void attn_blocks(const bf16_t* __restrict__ QKVP,
                                                   bf16_t* __restrict__ OUT1) {
  __shared__ __align__(16) bf16_t Qs[32][136];
  __shared__ __align__(16) bf16_t Ks[32][136];
  __shared__ __align__(16) bf16_t Vs[32][136];
  __shared__ __align__(16) bf16_t KVt[128][136];  // kv transposed: KVt[dd][f]
  __shared__ float ksum[128];
  __shared__ float zinv[32];

  const int tid  = threadIdx.x;
  const int lane = tid & 63;
  const int wave = tid >> 6;
  const int cblk = blockIdx.x & 127;
  const int h    = (blockIdx.x >> 7) & 7;
  const int b    = blockIdx.x >> 10;
  const size_t row0 = (size_t)b * 4096 + (size_t)cblk * 32;
  const bf16_t* base = QKVP + row0 * 3072 + h * 128;

  // stage qp, kp, v tiles (32 x 128 each) into padded LDS
#pragma unroll
  for (int mtx = 0; mtx < 3; ++mtx) {
    const bf16_t* src = base + mtx * 1024;
    bf16_t* dst = (mtx == 0) ? &Qs[0][0] : ((mtx == 1) ? &Ks[0][0] : &Vs[0][0]);
#pragma unroll
    for (int ch = 0; ch < 2; ++ch) {
      int id = tid + ch * 256;
      int r = id >> 4, cv = (id & 15) * 8;
      *(bf16x8*)(dst + r * 136 + cv) = *(const bf16x8*)(src + (size_t)r * 3072 + cv);
    }
  }
  __syncthreads();

  const int lr  = lane & 15;
  const int lk8 = (lane >> 4) * 8;

  // kv = kp^T * v : wave handles f-rows [wave*32, wave*32+32)
  f32x4 acc2[2][8] = {};
  bf16x8 afr[2];
#pragma unroll
  for (int ft = 0; ft < 2; ++ft) {
    int f = wave * 32 + ft * 16 + lr;
    bf16x8 v;
#pragma unroll
    for (int j = 0; j < 8; ++j) v[j] = Ks[lk8 + j][f];
    afr[ft] = v;
  }
#pragma unroll
  for (int dt = 0; dt < 8; ++dt) {
    bf16x8 bv;
#pragma unroll
    for (int j = 0; j < 8; ++j) bv[j] = Vs[lk8 + j][dt * 16 + lr];
#pragma unroll
    for (int ft = 0; ft < 2; ++ft)
      acc2[ft][dt] = mfma16x16x32(afr[ft], bv, acc2[ft][dt]);
  }
  // ksum[f] = sum_s kp[s][f]
  if (tid < 128) {
    float s = 0.f;
#pragma unroll
    for (int si = 0; si < 32; ++si) s += (float)Ks[si][tid];
    ksum[tid] = s;
  }
  // write kv transposed to LDS (bf16)
#pragma unroll
  for (int ft = 0; ft < 2; ++ft) {
#pragma unroll
    for (int dt = 0; dt < 8; ++dt) {
      int fb = wave * 32 + ft * 16 + (lane >> 4) * 4;
      int dd = dt * 16 + lr;
      bf16x4 pk;
#pragma unroll
      for (int r = 0; r < 4; ++r) pk[r] = (bf16_t)acc2[ft][dt][r];
      *(bf16x4*)(&KVt[dd][fb]) = pk;
    }
  }
  __syncthreads();

  // denom[m] = qp[m] . ksum ; 8 lanes per row
  {
    int m = tid >> 3, fc = tid & 7;
    float part = 0.f;
#pragma unroll
    for (int j = 0; j < 16; ++j) {
      int f = fc * 16 + j;
      part += (float)Qs[m][f] * ksum[f];
    }
    part += __shfl_xor(part, 1);
    part += __shfl_xor(part, 2);
    part += __shfl_xor(part, 4);
    if (fc == 0) zinv[m] = 1.0f / (part + 1e-8f);
  }
  __syncthreads();

  // num = qp * kv : wave handles dd-cols [wave*32, wave*32+32)
  f32x4 accN[2][2] = {};
#pragma unroll
  for (int ks = 0; ks < 4; ++ks) {
    bf16x8 aq[2], bk[2];
#pragma unroll
    for (int mt = 0; mt < 2; ++mt)
      aq[mt] = *(const bf16x8*)(&Qs[mt * 16 + lr][ks * 32 + lk8]);
#pragma unroll
    for (int nt = 0; nt < 2; ++nt)
      bk[nt] = *(const bf16x8*)(&KVt[wave * 32 + nt * 16 + lr][ks * 32 + lk8]);
#pragma unroll
    for (int mt = 0; mt < 2; ++mt)
#pragma unroll
      for (int nt = 0; nt < 2; ++nt)
        accN[mt][nt] = mfma16x16x32(aq[mt], bk[nt], accN[mt][nt]);
  }

  // out = num * z ; write bf16 to OUT1 (16384 x 1024)
  bf16_t* obase = OUT1 + row0 * 1024 + h * 128;
#pragma unroll
  for (int mt = 0; mt < 2; ++mt) {
#pragma unroll
    for (int nt = 0; nt < 2; ++nt) {
      int dd = wave * 32 + nt * 16 + lr;
      int mb = mt * 16 + (lane >> 4) * 4;
#pragma unroll
      for (int r = 0; r < 4; ++r) {
        int m = mb + r;
        float v = accN[mt][nt][r] * zinv[m];
        obase[(size_t)m * 1024 + dd] = (bf16_t)v;
      }
    }
  }
}

// ---------------------------------------------------------------- launch
extern "C" void kernel_launch(void* const* d_in, const int* in_sizes, int n_in,
                              void* d_out, int out_size, void* d_ws, size_t ws_size,
                              hipStream_t stream) {
  const float* x     = (const float*)d_in[0];
  const float* w_qkv = (const float*)d_in[1];
  const float* w_out = (const float*)d_in[2];
  const float* b_out = (const float*)d_in[3];
  const float* proj  = (const float*)d_in[4];
  float* out = (float*)d_out;

  char* ws = (char*)d_ws;
  // layout (bytes): xbf/OUT1 [0,32M) | B1t [32M,38M) | W3t [38M,40M) | QKVP [40M,136M)
  bf16_t* xbf  = (bf16_t*)(ws);
  bf16_t* B1t  = (bf16_t*)(ws + 33554432);
  bf16_t* W3t  = (bf16_t*)(ws + 39845888);
  bf16_t* QKVP = (bf16_t*)(ws + 41943040);
  bf16_t* OUT1 = xbf;  // reuse: xbf dead after stage-1 GEMM

  (void)in_sizes; (void)n_in; (void)out_size; (void)ws_size;

  // converts
  cvt_bf16<<<1024, 256, 0, stream>>>(x, xbf, 16777216);
  cvt_bf16<<<256, 256, 0, stream>>>(w_out, W3t, 1048576);
  cvt_bf16<<<256, 256, 0, stream>>>(w_qkv + (size_t)2048 * 1024, B1t + (size_t)2048 * 1024, 1048576);
  // fused qp/kp weights
  fuse_w<<<256, 256, 0, stream>>>(w_qkv, proj, B1t);
  // stage 1: [qp | kp | v] = x @ B1t^T, elu+1 on first 2048 cols
  gemm_bt<1><<<dim3(24, 128), 256, 0, stream>>>(xbf, B1t, (void*)QKVP, nullptr,
                                                16384, 3072, 1024, 2048);
  // stage 2: per-block linear attention
  attn_blocks<<<4096, 256, 0, stream>>>(QKVP, OUT1);
  // stage 3: out = OUT1 @ w_out^T + b_out (f32)
  gemm_bt<2><<<dim3(8, 128), 256, 0, stream>>>(OUT1, W3t, (void*)out, b_out,
                                               16384, 1024, 1024, 0);
}

// Round 2
// 265.721 us; speedup vs baseline: 1.1745x; 1.1745x over previous
//
#include <hip/hip_runtime.h>
#include <hip/hip_bf16.h>
#include <stdint.h>
#include <stddef.h>

typedef __bf16 bf16_t;
typedef __bf16 bf16x8 __attribute__((ext_vector_type(8)));
typedef __bf16 bf16x4 __attribute__((ext_vector_type(4)));
typedef float  f32x4  __attribute__((ext_vector_type(4)));

static __device__ __forceinline__ f32x4 mfma16x16x32(bf16x8 a, bf16x8 b, f32x4 c) {
  return __builtin_amdgcn_mfma_f32_16x16x32_bf16(a, b, c, 0, 0, 0);
}

static __device__ __forceinline__ void gld_lds16(const void* g, void* l) {
  __builtin_amdgcn_global_load_lds(
      (const __attribute__((address_space(1))) unsigned int*)g,
      (__attribute__((address_space(3))) unsigned int*)l, 16, 0, 0);
}

#define BARW()   __builtin_amdgcn_s_barrier()
#define SCHED0() __builtin_amdgcn_sched_barrier(0)
#define LGKM0()  asm volatile("s_waitcnt lgkmcnt(0)" ::: "memory")
#define VMCNT(n) asm volatile("s_waitcnt vmcnt(" #n ")" ::: "memory")
#define PRIO(p)  __builtin_amdgcn_s_setprio(p)

// ---------------------------------------------------------------- cvt f32->bf16
__global__ __launch_bounds__(256) void cvt_bf16(const float* __restrict__ in,
                                                bf16_t* __restrict__ out, int n) {
  int stride = gridDim.x * blockDim.x;
  for (int i = blockIdx.x * blockDim.x + threadIdx.x; i * 4 < n; i += stride) {
    float4 v = *(const float4*)(in + (size_t)i * 4);
    bf16x4 o;
    o[0] = (bf16_t)v.x; o[1] = (bf16_t)v.y; o[2] = (bf16_t)v.z; o[3] = (bf16_t)v.w;
    *(bf16x4*)(out + (size_t)i * 4) = o;
  }
}

// ---------------------------------------------------------------- fused weights
__global__ __launch_bounds__(256) void fuse_w(const float* __restrict__ wqkv,
                                              const float* __restrict__ proj,
                                              bf16_t* __restrict__ B1t) {
  const int blk    = blockIdx.x;
  const int combo  = blk >> 4;       // qk*8 + h
  const int kt     = blk & 15;
  const int qk     = combo >> 3;
  const int h      = combo & 7;
  const int klocal = threadIdx.x & 63;
  const int fg     = threadIdx.x >> 6;  // 0..3
  const int k      = kt * 64 + klocal;

  const float* wbase = wqkv + ((size_t)(qk * 1024 + h * 128)) * 1024 + k;
  const float* pbase = proj + (size_t)h * 16384 + fg * 32;

  float acc[32];
#pragma unroll
  for (int i = 0; i < 32; ++i) acc[i] = 0.f;

  for (int c = 0; c < 128; ++c) {
    float a = wbase[(size_t)c * 1024];
    const float4* p = (const float4*)(pbase + (size_t)c * 128);
#pragma unroll
    for (int i = 0; i < 8; ++i) {
      float4 pv = p[i];
      acc[i * 4 + 0] += a * pv.x;
      acc[i * 4 + 1] += a * pv.y;
      acc[i * 4 + 2] += a * pv.z;
      acc[i * 4 + 3] += a * pv.w;
    }
  }
  bf16_t* obase = B1t + ((size_t)(qk * 1024 + h * 128 + fg * 32)) * 1024 + k;
#pragma unroll
  for (int i = 0; i < 32; ++i) obase[(size_t)i * 1024] = (bf16_t)acc[i];
}

// ---------------------------------------------------------------- 256^2 8-phase GEMM
// C[M][N] = A[M][K] * Bt[N][K]^T ; EPI 1 = bf16 out + elu+1 for n<elu_n ; 2 = f32 out + bias
template <int EPI>
__global__ __launch_bounds__(512, 2) void gemm256(const bf16_t* __restrict__ A,
                                                  const bf16_t* __restrict__ Bt,
                                                  void* __restrict__ Cout,
                                                  const float* __restrict__ bias,
                                                  int N, int K, int elu_n, int NB) {
  __shared__ __align__(16) bf16_t sA[2][2][8192];  // [buf][half(row 0-127 / 128-255)][128*64]
  __shared__ __align__(16) bf16_t sB[2][2][8192];
  const int tid  = threadIdx.x;
  const int lane = tid & 63;
  const int wid  = tid >> 6;
  const int wm   = wid >> 2;   // 0..1
  const int wn   = wid & 3;    // 0..3
  const int lr   = lane & 15;
  const int g0   = lane >> 4;  // 0..3

  // bijective XCD swizzle (grid % 8 == 0)
  const int nwg = gridDim.x;
  const int cpx = nwg >> 3;
  const int bid = blockIdx.x;
  const int swz = (bid & 7) * cpx + (bid >> 3);
  const int m0 = (swz / NB) * 256;
  const int n0 = (swz % NB) * 256;

  const int NT = K >> 6;

  // staging: 2 x 16B per thread per half-tile; inverse swizzle on global source
  int srow[2], sgl[2];
#pragma unroll
  for (int l = 0; l < 2; ++l) {
    int idx = l * 512 + tid;
    srow[l] = idx >> 3;
    sgl[l]  = (idx & 7) ^ (srow[l] & 7);
  }
  const bf16_t* Abase = A  + (size_t)m0 * K;
  const bf16_t* Bbase = Bt + (size_t)n0 * K;

#define STAGE_A(buf, half, kt)                                                 \
  {                                                                            \
    const bf16_t* s_ = Abase + (size_t)((half) * 128) * K + (kt) * 64;         \
    bf16_t* d_ = &sA[buf][half][0];                                            \
    _Pragma("unroll")                                                          \
    for (int l_ = 0; l_ < 2; ++l_)                                             \
      gld_lds16(s_ + (size_t)srow[l_] * K + sgl[l_] * 8,                       \
                d_ + (l_ * 512 + tid) * 8);                                    \
  }
#define STAGE_B(buf, half, kt)                                                 \
  {                                                                            \
    const bf16_t* s_ = Bbase + (size_t)((half) * 128) * K + (kt) * 64;         \
    bf16_t* d_ = &sB[buf][half][0];                                            \
    _Pragma("unroll")                                                          \
    for (int l_ = 0; l_ < 2; ++l_)                                             \
      gld_lds16(s_ + (size_t)srow[l_] * K + sgl[l_] * 8,                       \
                d_ + (l_ * 512 + tid) * 8);                                    \
  }

  f32x4 acc[8][4] = {};
  bf16x8 a[4][2], b0[2][2], b1[2][2];

#define RD_A(buf, qm)                                                          \
  _Pragma("unroll")                                                            \
  for (int t_ = 0; t_ < 4; ++t_) {                                             \
    int r_ = (qm) * 64 + t_ * 16 + lr;                                         \
    _Pragma("unroll")                                                          \
    for (int kh_ = 0; kh_ < 2; ++kh_) {                                        \
      int gl_ = (g0 + kh_ * 4) ^ (r_ & 7);                                     \
      a[t_][kh_] = *(const bf16x8*)(&sA[buf][wm][r_ * 64 + gl_ * 8]);          \
    }                                                                          \
  }
#define RD_B(buf, qn, breg)                                                    \
  _Pragma("unroll")                                                            \
  for (int u_ = 0; u_ < 2; ++u_) {                                             \
    int r_ = (wn & 1) * 64 + (qn) * 32 + u_ * 16 + lr;                         \
    _Pragma("unroll")                                                          \
    for (int kh_ = 0; kh_ < 2; ++kh_) {                                        \
      int gl_ = (g0 + kh_ * 4) ^ (r_ & 7);                                     \
      breg[u_][kh_] = *(const bf16x8*)(&sB[buf][wn >> 1][r_ * 64 + gl_ * 8]);  \
    }                                                                          \
  }
#define MMA(qm, qn, breg)                                                      \
  _Pragma("unroll")                                                            \
  for (int mi_ = 0; mi_ < 4; ++mi_)                                            \
    _Pragma("unroll")                                                          \
    for (int nj_ = 0; nj_ < 2; ++nj_)                                          \
      _Pragma("unroll")                                                        \
      for (int kh_ = 0; kh_ < 2; ++kh_)                                        \
        acc[(qm) * 4 + mi_][(qn) * 2 + nj_] =                                  \
            mfma16x16x32(a[mi_][kh_], breg[nj_][kh_],                          \
                         acc[(qm) * 4 + mi_][(qn) * 2 + nj_]);

  // prologue: kt0 -> buf0, kt1 -> buf1
  STAGE_A(0, 0, 0); STAGE_A(0, 1, 0); STAGE_B(0, 0, 0); STAGE_B(0, 1, 0);
  STAGE_A(1, 0, 1); STAGE_A(1, 1, 1); STAGE_B(1, 0, 1); STAGE_B(1, 1, 1);
  VMCNT(8);
  BARW();

#pragma unroll 2
  for (int j = 0; j < NT; ++j) {
    const int cur = j & 1;
    const bool pf = (j + 2) < NT;
    // ---- P1: read A[qm=0] + B[qn=0]; MFMA quadrant (0,0)
    RD_A(cur, 0);
    RD_B(cur, 0, b0);
    SCHED0(); BARW(); LGKM0(); SCHED0();
    PRIO(1); MMA(0, 0, b0); PRIO(0);
    SCHED0(); BARW();
    // ---- P2: read B[qn=1]; MFMA (0,1)
    RD_B(cur, 1, b1);
    SCHED0(); BARW(); LGKM0(); SCHED0();
    PRIO(1); MMA(0, 1, b1); PRIO(0);
    SCHED0(); BARW();
    // ---- P3: read A[qm=1]; stage B(kt j+2) into cur (B reads done at P2); MFMA (1,1)
    RD_A(cur, 1);
    if (pf) { STAGE_B(cur, 0, j + 2); STAGE_B(cur, 1, j + 2); }
    SCHED0(); BARW(); LGKM0(); SCHED0();
    PRIO(1); MMA(1, 1, b1); PRIO(0);
    SCHED0(); BARW();
    // ---- P4: stage A(kt j+2) into cur (A reads done at P3); MFMA (1,0)
    if (pf) { STAGE_A(cur, 0, j + 2); STAGE_A(cur, 1, j + 2); }
    SCHED0(); BARW();
    PRIO(1); MMA(1, 0, b0); PRIO(0);
    if (pf) { VMCNT(8); } else { VMCNT(0); }
    SCHED0(); BARW();
  }

  // epilogue: C/D layout col=lane&15, row=(lane>>4)*4+r
#pragma unroll
  for (int i = 0; i < 8; ++i) {
#pragma unroll
    for (int jn = 0; jn < 4; ++jn) {
      const int n = n0 + wn * 64 + jn * 16 + lr;
#pragma unroll
      for (int r = 0; r < 4; ++r) {
        const int m = m0 + wm * 128 + i * 16 + g0 * 4 + r;
        float v = acc[i][jn][r];
        if constexpr (EPI == 1) {
          if (n < elu_n) v = (v > 0.f) ? (v + 1.f) : __expf(v);
          ((bf16_t*)Cout)[(size_t)m * N + n] = (bf16_t)v;
        } else {
          ((float*)Cout)[(size_t)m * N + n] = v + bias[n];
        }
      }
    }
  }
#undef STAGE_A
#undef STAGE_B
#undef RD_A
#undef RD_B
#undef MMA
}

// ---------------------------------------------------------------- block attention
__global__ __launch_bounds__(256) void attn_blocks(const bf16_t* __restrict__ QKVP,
                                                   bf16_t* __restrict__ OUT1) {
  __shared__ __align__(16) bf16_t Qs[32][136];
  __shared__ __align__(16) bf16_t Ks[32][136];
  __shared__ __align__(16) bf16_t Vs[32][136];
  __shared__ __align__(16) bf16_t KVt[128][136];  // kv transposed: KVt[dd][f]
  __shared__ float ksum[128];
  __shared__ float zinv[32];

  const int tid  = threadIdx.x;
  const int lane = tid & 63;
  const int wave = tid >> 6;
  const int cblk = blockIdx.x & 127;
  const int h    = (blockIdx.x >> 7) & 7;
  const int b    = blockIdx.x >> 10;
  const size_t row0 = (size_t)b * 4096 + (size_t)cblk * 32;
  const bf16_t* base = QKVP + row0 * 3072 + h * 128;

#pragma unroll
  for (int mtx = 0; mtx < 3; ++mtx) {
    const bf16_t* src = base + mtx * 1024;
    bf16_t* dst = (mtx == 0) ? &Qs[0][0] : ((mtx == 1) ? &Ks[0][0] : &Vs[0][0]);
#pragma unroll
    for (int ch = 0; ch < 2; ++ch) {
      int id = tid + ch * 256;
      int r = id >> 4, cv = (id & 15) * 8;
      *(bf16x8*)(dst + r * 136 + cv) = *(const bf16x8*)(src + (size_t)r * 3072 + cv);
    }
  }
  __syncthreads();

  const int lr  = lane & 15;
  const int lk8 = (lane >> 4) * 8;

  // kv = kp^T * v : wave handles f-rows [wave*32, wave*32+32)
  f32x4 acc2[2][8] = {};
  bf16x8 afr[2];
#pragma unroll
  for (int ft = 0; ft < 2; ++ft) {
    int f = wave * 32 + ft * 16 + lr;
    bf16x8 v;
#pragma unroll
    for (int j = 0; j < 8; ++j) v[j] = Ks[lk8 + j][f];
    afr[ft] = v;
  }
#pragma unroll
  for (int dt = 0; dt < 8; ++dt) {
    bf16x8 bv;
#pragma unroll
    for (int j = 0; j < 8; ++j) bv[j] = Vs[lk8 + j][dt * 16 + lr];
#pragma unroll
    for (int ft = 0; ft < 2; ++ft)
      acc2[ft][dt] = mfma16x16x32(afr[ft], bv, acc2[ft][dt]);
  }
  if (tid < 128) {
    float s = 0.f;
#pragma unroll
    for (int si = 0; si < 32; ++si) s += (float)Ks[si][tid];
    ksum[tid] = s;
  }
#pragma unroll
  for (int ft = 0; ft < 2; ++ft) {
#pragma unroll
    for (int dt = 0; dt < 8; ++dt) {
      int fb = wave * 32 + ft * 16 + (lane >> 4) * 4;
      int dd = dt * 16 + lr;
      bf16x4 pk;
#pragma unroll
      for (int r = 0; r < 4; ++r) pk[r] = (bf16_t)acc2[ft][dt][r];
      *(bf16x4*)(&KVt[dd][fb]) = pk;
    }
  }
  __syncthreads();

  {
    int m = tid >> 3, fc = tid & 7;
    float part = 0.f;
#pragma unroll
    for (int j = 0; j < 16; ++j) {
      int f = fc * 16 + j;
      part += (float)Qs[m][f] * ksum[f];
    }
    part += __shfl_xor(part, 1);
    part += __shfl_xor(part, 2);
    part += __shfl_xor(part, 4);
    if (fc == 0) zinv[m] = 1.0f / (part + 1e-8f);
  }
  __syncthreads();

  f32x4 accN[2][2] = {};
#pragma unroll
  for (int ks = 0; ks < 4; ++ks) {
    bf16x8 aq[2], bk[2];
#pragma unroll
    for (int mt = 0; mt < 2; ++mt)
      aq[mt] = *(const bf16x8*)(&Qs[mt * 16 + lr][ks * 32 + lk8]);
#pragma unroll
    for (int nt = 0; nt < 2; ++nt)
      bk[nt] = *(const bf16x8*)(&KVt[wave * 32 + nt * 16 + lr][ks * 32 + lk8]);
#pragma unroll
    for (int mt = 0; mt < 2; ++mt)
#pragma unroll
      for (int nt = 0; nt < 2; ++nt)
        accN[mt][nt] = mfma16x16x32(aq[mt], bk[nt], accN[mt][nt]);
  }

  bf16_t* obase = OUT1 + row0 * 1024 + h * 128;
#pragma unroll
  for (int mt = 0; mt < 2; ++mt) {
#pragma unroll
    for (int nt = 0; nt < 2; ++nt) {
      int dd = wave * 32 + nt * 16 + lr;
      int mb = mt * 16 + (lane >> 4) * 4;
#pragma unroll
      for (int r = 0; r < 4; ++r) {
        int m = mb + r;
        float v = accN[mt][nt][r] * zinv[m];
        obase[(size_t)m * 1024 + dd] = (bf16_t)v;
      }
    }
  }
}

// ---------------------------------------------------------------- launch
extern "C" void kernel_launch(void* const* d_in, const int* in_sizes, int n_in,
                              void* d_out, int out_size, void* d_ws, size_t ws_size,
                              hipStream_t stream) {
  const float* x     = (const float*)d_in[0];
  const float* w_qkv = (const float*)d_in[1];
  const float* w_out = (const float*)d_in[2];
  const float* b_out = (const float*)d_in[3];
  const float* proj  = (const float*)d_in[4];
  float* out = (float*)d_out;

  char* ws = (char*)d_ws;
  // layout (bytes): xbf/OUT1 [0,32M) | B1t [32M,38M) | W3t [38M,40M) | QKVP [40M,136M)
  bf16_t* xbf  = (bf16_t*)(ws);
  bf16_t* B1t  = (bf16_t*)(ws + 33554432);
  bf16_t* W3t  = (bf16_t*)(ws + 39845888);
  bf16_t* QKVP = (bf16_t*)(ws + 41943040);
  bf16_t* OUT1 = xbf;  // reuse: xbf dead after stage-1 GEMM

  (void)in_sizes; (void)n_in; (void)out_size; (void)ws_size;

  cvt_bf16<<<1024, 256, 0, stream>>>(x, xbf, 16777216);
  cvt_bf16<<<256, 256, 0, stream>>>(w_out, W3t, 1048576);
  cvt_bf16<<<256, 256, 0, stream>>>(w_qkv + (size_t)2048 * 1024, B1t + (size_t)2048 * 1024, 1048576);
  fuse_w<<<256, 256, 0, stream>>>(w_qkv, proj, B1t);
  // stage 1: [qp | kp | v] = x @ B1t^T, elu+1 on first 2048 cols
  gemm256<1><<<768, 512, 0, stream>>>(xbf, B1t, (void*)QKVP, nullptr, 3072, 1024, 2048, 12);
  // stage 2: per-block linear attention
  attn_blocks<<<4096, 256, 0, stream>>>(QKVP, OUT1);
  // stage 3: out = OUT1 @ w_out^T + b_out (f32)
  gemm256<2><<<256, 512, 0, stream>>>(OUT1, W3t, (void*)out, b_out, 1024, 1024, 0, 4);
}

// Round 4
// 238.870 us; speedup vs baseline: 1.3066x; 1.1124x over previous
//
#include <hip/hip_runtime.h>
#include <hip/hip_bf16.h>
#include <stdint.h>
#include <stddef.h>

typedef __bf16 bf16_t;
typedef __bf16 bf16x8 __attribute__((ext_vector_type(8)));
typedef __bf16 bf16x4 __attribute__((ext_vector_type(4)));
typedef float  f32x4  __attribute__((ext_vector_type(4)));

static __device__ __forceinline__ f32x4 mfma16x16x32(bf16x8 a, bf16x8 b, f32x4 c) {
  return __builtin_amdgcn_mfma_f32_16x16x32_bf16(a, b, c, 0, 0, 0);
}

static __device__ __forceinline__ void gld_lds16(const void* g, void* l) {
  __builtin_amdgcn_global_load_lds(
      (const __attribute__((address_space(1))) unsigned int*)g,
      (__attribute__((address_space(3))) unsigned int*)l, 16, 0, 0);
}

#define BARW()   __builtin_amdgcn_s_barrier()
#define SCHED0() __builtin_amdgcn_sched_barrier(0)
#define LGKM0()  asm volatile("s_waitcnt lgkmcnt(0)" ::: "memory")
#define VMCNT(n) asm volatile("s_waitcnt vmcnt(" #n ")" ::: "memory")
#define PRIO(p)  __builtin_amdgcn_s_setprio(p)

// ---------------------------------------------------------------- cvt f32->bf16
__global__ __launch_bounds__(256) void cvt_bf16(const float* __restrict__ in,
                                                bf16_t* __restrict__ out, int n) {
  int stride = gridDim.x * blockDim.x;
  for (int i = blockIdx.x * blockDim.x + threadIdx.x; i * 4 < n; i += stride) {
    float4 v = *(const float4*)(in + (size_t)i * 4);
    bf16x4 o;
    o[0] = (bf16_t)v.x; o[1] = (bf16_t)v.y; o[2] = (bf16_t)v.z; o[3] = (bf16_t)v.w;
    *(bf16x4*)(out + (size_t)i * 4) = o;
  }
}

// ---------------------------------------------------------------- fused weights
// B1t2[h*256 + qk*128 + f][k] = sum_c w_qkv[(qk*1024+h*128+c)][k] * proj[h][c][f]
__global__ __launch_bounds__(256) void fuse_w(const float* __restrict__ wqkv,
                                              const float* __restrict__ proj,
                                              bf16_t* __restrict__ B1t2) {
  const int blk    = blockIdx.x;        // 0..255
  const int combo  = blk >> 4;          // qk*8 + h  (qk in 0..1)
  const int kt     = blk & 15;
  const int qk     = combo >> 3;
  const int h      = combo & 7;
  const int klocal = threadIdx.x & 63;
  const int fg     = threadIdx.x >> 6;  // 0..3
  const int k      = kt * 64 + klocal;

  const float* wbase = wqkv + ((size_t)(qk * 1024 + h * 128)) * 1024 + k;
  const float* pbase = proj + (size_t)h * 16384 + fg * 32;

  float acc[32];
#pragma unroll
  for (int i = 0; i < 32; ++i) acc[i] = 0.f;

  for (int c = 0; c < 128; ++c) {
    float a = wbase[(size_t)c * 1024];
    const float4* p = (const float4*)(pbase + (size_t)c * 128);
#pragma unroll
    for (int i = 0; i < 8; ++i) {
      float4 pv = p[i];
      acc[i * 4 + 0] += a * pv.x;
      acc[i * 4 + 1] += a * pv.y;
      acc[i * 4 + 2] += a * pv.z;
      acc[i * 4 + 3] += a * pv.w;
    }
  }
  bf16_t* obase = B1t2 + ((size_t)(h * 256 + qk * 128 + fg * 32)) * 1024 + k;
#pragma unroll
  for (int i = 0; i < 32; ++i) obase[(size_t)i * 1024] = (bf16_t)acc[i];
}

// ================================================================ shared main-loop macros
#define GEMM_MAINLOOP_DECLS()                                                  \
  const int tid  = threadIdx.x;                                                \
  const int lane = tid & 63;                                                   \
  const int wid  = tid >> 6;                                                   \
  const int wm   = wid >> 2;                                                   \
  const int wn   = wid & 3;                                                    \
  const int lr   = lane & 15;                                                  \
  const int g0   = lane >> 4;                                                  \
  int srow[2], sgl[2];                                                         \
  _Pragma("unroll")                                                            \
  for (int l = 0; l < 2; ++l) {                                                \
    int idx = l * 512 + tid;                                                   \
    srow[l] = idx >> 3;                                                        \
    sgl[l]  = (idx & 7) ^ (srow[l] & 7);                                       \
  }

// arr must be a 2D slice: sA[buf] / sB[buf]
#define STAGE_T(arr, base, half, kt, K_)                                       \
  {                                                                            \
    const bf16_t* s_ = (base) + (size_t)((half) * 128) * (K_) + (kt) * 64;     \
    bf16_t* d_ = &(arr)[half][0];                                              \
    _Pragma("unroll")                                                          \
    for (int l_ = 0; l_ < 2; ++l_)                                             \
      gld_lds16(s_ + (size_t)srow[l_] * (K_) + sgl[l_] * 8,                    \
                d_ + (l_ * 512 + tid) * 8);                                    \
  }

#define RD_A(buf, qm)                                                          \
  _Pragma("unroll")                                                            \
  for (int t_ = 0; t_ < 4; ++t_) {                                             \
    int r_ = (qm) * 64 + t_ * 16 + lr;                                         \
    _Pragma("unroll")                                                          \
    for (int kh_ = 0; kh_ < 2; ++kh_) {                                        \
      int gl_ = (g0 + kh_ * 4) ^ (r_ & 7);                                     \
      a[t_][kh_] = *(const bf16x8*)(&sA[buf][wm][r_ * 64 + gl_ * 8]);          \
    }                                                                          \
  }
#define RD_B(buf, qn, breg)                                                    \
  _Pragma("unroll")                                                            \
  for (int u_ = 0; u_ < 2; ++u_) {                                             \
    int r_ = (wn & 1) * 64 + (qn) * 32 + u_ * 16 + lr;                         \
    _Pragma("unroll")                                                          \
    for (int kh_ = 0; kh_ < 2; ++kh_) {                                        \
      int gl_ = (g0 + kh_ * 4) ^ (r_ & 7);                                     \
      breg[u_][kh_] = *(const bf16x8*)(&sB[buf][wn >> 1][r_ * 64 + gl_ * 8]);  \
    }                                                                          \
  }
#define MMA(qm, qn, breg)                                                      \
  _Pragma("unroll")                                                            \
  for (int mi_ = 0; mi_ < 4; ++mi_)                                            \
    _Pragma("unroll")                                                          \
    for (int nj_ = 0; nj_ < 2; ++nj_)                                          \
      _Pragma("unroll")                                                        \
      for (int kh_ = 0; kh_ < 2; ++kh_)                                        \
        acc[(qm) * 4 + mi_][(qn) * 2 + nj_] =                                  \
            mfma16x16x32(a[mi_][kh_], breg[nj_][kh_],                          \
                         acc[(qm) * 4 + mi_][(qn) * 2 + nj_]);

#define GEMM_MAINLOOP_BODY(Abase, Bbase, K_, NT_)                              \
  f32x4 acc[8][4] = {};                                                        \
  bf16x8 a[4][2], b0[2][2], b1[2][2];                                          \
  STAGE_T(sA[0], Abase, 0, 0, K_); STAGE_T(sA[0], Abase, 1, 0, K_);            \
  STAGE_T(sB[0], Bbase, 0, 0, K_); STAGE_T(sB[0], Bbase, 1, 0, K_);            \
  STAGE_T(sA[1], Abase, 0, 1, K_); STAGE_T(sA[1], Abase, 1, 1, K_);            \
  STAGE_T(sB[1], Bbase, 0, 1, K_); STAGE_T(sB[1], Bbase, 1, 1, K_);            \
  VMCNT(8);                                                                    \
  BARW();                                                                      \
  _Pragma("unroll 2")                                                          \
  for (int j = 0; j < (NT_); ++j) {                                            \
    const int cur = j & 1;                                                     \
    const bool pf = (j + 2) < (NT_);                                           \
    RD_A(cur, 0);                                                              \
    RD_B(cur, 0, b0);                                                          \
    SCHED0(); BARW(); LGKM0(); SCHED0();                                       \
    PRIO(1); MMA(0, 0, b0); PRIO(0);                                           \
    SCHED0(); BARW();                                                          \
    RD_B(cur, 1, b1);                                                          \
    SCHED0(); BARW(); LGKM0(); SCHED0();                                       \
    PRIO(1); MMA(0, 1, b1); PRIO(0);                                           \
    SCHED0(); BARW();                                                          \
    RD_A(cur, 1);                                                              \
    if (pf) { STAGE_T(sB[cur], Bbase, 0, j + 2, K_); STAGE_T(sB[cur], Bbase, 1, j + 2, K_); } \
    SCHED0(); BARW(); LGKM0(); SCHED0();                                       \
    PRIO(1); MMA(1, 1, b1); PRIO(0);                                           \
    SCHED0(); BARW();                                                          \
    if (pf) { STAGE_T(sA[cur], Abase, 0, j + 2, K_); STAGE_T(sA[cur], Abase, 1, j + 2, K_); } \
    SCHED0(); BARW();                                                          \
    PRIO(1); MMA(1, 0, b0); PRIO(0);                                           \
    if (pf) { VMCNT(8); } else { VMCNT(0); }                                   \
    SCHED0(); BARW();                                                          \
  }

// ---------------------------------------------------------------- 256^2 8-phase GEMM
// EPI 2: f32 out + bias    EPI 3: bf16 out row-major (no bias)
template <int EPI>
__global__ __launch_bounds__(512, 2) void gemm256(const bf16_t* __restrict__ A,
                                                  const bf16_t* __restrict__ Bt,
                                                  void* __restrict__ Cout,
                                                  const float* __restrict__ bias,
                                                  int N, int K, int NB) {
  __shared__ __align__(16) bf16_t sA[2][2][8192];
  __shared__ __align__(16) bf16_t sB[2][2][8192];
  GEMM_MAINLOOP_DECLS();

  const int nwg = gridDim.x;
  const int cpx = nwg >> 3;
  const int bid = blockIdx.x;
  const int swz = (bid & 7) * cpx + (bid >> 3);
  const int m0 = (swz / NB) * 256;
  const int n0 = (swz % NB) * 256;
  const int NT = K >> 6;

  const bf16_t* Abase = A  + (size_t)m0 * K;
  const bf16_t* Bbase = Bt + (size_t)n0 * K;

  GEMM_MAINLOOP_BODY(Abase, Bbase, K, NT);

#pragma unroll
  for (int i = 0; i < 8; ++i) {
#pragma unroll
    for (int jn = 0; jn < 4; ++jn) {
      const int n = n0 + wn * 64 + jn * 16 + lr;
#pragma unroll
      for (int r = 0; r < 4; ++r) {
        const int m = m0 + wm * 128 + i * 16 + g0 * 4 + r;
        float v = acc[i][jn][r];
        if constexpr (EPI == 2) {
          ((float*)Cout)[(size_t)m * N + n] = v + bias[n];
        } else {
          ((bf16_t*)Cout)[(size_t)m * N + n] = (bf16_t)v;
        }
      }
    }
  }
}

// ---------------------------------------------------------------- fused qp/kp GEMM + block attention
// Block (mtile, h): [qp|kp] (256 x 256) for head h; per 32-row c-block:
// S = qp kp^T (32x32), z = rowsum(S), out = (S/z) v  -> OUT1[m][h*128+d]
__global__ __launch_bounds__(512, 2) void gemm_fused(const bf16_t* __restrict__ A,
                                                     const bf16_t* __restrict__ Bt,
                                                     const bf16_t* __restrict__ VtG,
                                                     bf16_t* __restrict__ OUT1) {
  __shared__ __align__(16) bf16_t sA[2][2][8192];
  __shared__ __align__(16) bf16_t sB[2][2][8192];
  GEMM_MAINLOOP_DECLS();

  const int nwg = gridDim.x;          // 512
  const int cpx = nwg >> 3;
  const int bid = blockIdx.x;
  const int swz = (bid & 7) * cpx + (bid >> 3);
  const int m0 = (swz >> 3) * 256;
  const int h  = swz & 7;
  const int K  = 1024;
  const int NT = 16;

  const bf16_t* Abase = A  + (size_t)m0 * K;
  const bf16_t* Bbase = Bt + (size_t)(h * 256) * K;

  GEMM_MAINLOOP_BODY(Abase, Bbase, K, NT);

  // ---------------- fused attention epilogue ----------------
  char* sQb = (char*)(&sA[0][0][0]);   // Qp: 256 rows x 256B (swizzled granules)
  char* sKb = (char*)(&sB[0][0][0]);   // Kp: same; later reused for Vt (128 x 512B)

  // ep1: elu+1, cvt, scatter acc -> LDS
  {
    char* dbase = (wn < 2) ? sQb : sKb;
#pragma unroll
    for (int i = 0; i < 8; ++i)
#pragma unroll
      for (int jn = 0; jn < 4; ++jn)
#pragma unroll
        for (int r = 0; r < 4; ++r) {
          int row = wm * 128 + i * 16 + g0 * 4 + r;
          int col = (wn & 1) * 64 + jn * 16 + lr;     // 0..127 within Q or K
          float v = acc[i][jn][r];
          v = v > 0.f ? v + 1.f : __expf(v);
          int gq = col >> 3;
          int g  = (gq & 8) | ((gq ^ row) & 7);
          *(bf16_t*)(dbase + row * 256 + g * 16 + (col & 7) * 2) = (bf16_t)v;
        }
  }
  LGKM0();
  BARW();

  // ep2: S = qp kp^T for this wave's c-block
  const int cb = wm * 4 + wn;          // 0..7
  const int rb = cb * 32;              // row base of c-block
  f32x4 sacc[2][2] = {};
#pragma unroll
  for (int kh = 0; kh < 4; ++kh) {
    bf16x8 aS[2], bS[2];
#pragma unroll
    for (int t = 0; t < 2; ++t) {
      int row = rb + t * 16 + lr;
      int gq = kh * 4 + g0;
      int g  = (gq & 8) | ((gq ^ row) & 7);
      aS[t] = *(const bf16x8*)(sQb + row * 256 + g * 16);
      bS[t] = *(const bf16x8*)(sKb + row * 256 + g * 16);
    }
#pragma unroll
    for (int mt = 0; mt < 2; ++mt)
#pragma unroll
      for (int nt = 0; nt < 2; ++nt)
        sacc[mt][nt] = mfma16x16x32(aS[mt], bS[nt], sacc[mt][nt]);
  }

  // rowsum over j -> zinv
  float zin[2][4];
#pragma unroll
  for (int mt = 0; mt < 2; ++mt)
#pragma unroll
    for (int r = 0; r < 4; ++r) {
      float s = sacc[mt][0][r] + sacc[mt][1][r];
      s += __shfl_xor(s, 1); s += __shfl_xor(s, 2);
      s += __shfl_xor(s, 4); s += __shfl_xor(s, 8);
      zin[mt][r] = 1.0f / (s + 1e-8f);
    }
  BARW();   // all S-reads done; LDS reusable

  // ep3: P -> Pl (sA region, 8 x [32 x 80B]), stage Vt -> sB (128 x 512B)
  char* Pl = sQb;
#pragma unroll
  for (int mt = 0; mt < 2; ++mt)
#pragma unroll
    for (int nt = 0; nt < 2; ++nt)
#pragma unroll
      for (int r = 0; r < 4; ++r) {
        int i = mt * 16 + g0 * 4 + r;
        int jj = nt * 16 + lr;
        *(bf16_t*)(Pl + cb * 2560 + i * 80 + jj * 2) =
            (bf16_t)(sacc[mt][nt][r] * zin[mt][r]);
      }
  {
#pragma unroll
    for (int l = 0; l < 8; ++l) {
      int gd = l * 512 + tid;
      int row = gd >> 5, gcol = gd & 31;
      const bf16_t* src = VtG + (size_t)(h * 128 + row) * 16384 + m0 +
                          ((gcol ^ (row & 7)) * 8);
      gld_lds16(src, sKb + gd * 16);
    }
  }
  VMCNT(0);
  LGKM0();
  BARW();

  // ep4: out = P . v  (one MFMA per (mt,dt)), write OUT1
  bf16x8 aP[2];
#pragma unroll
  for (int mt = 0; mt < 2; ++mt)
    aP[mt] = *(const bf16x8*)(Pl + cb * 2560 + (mt * 16 + lr) * 80 + g0 * 16);
#pragma unroll
  for (int dt = 0; dt < 8; ++dt) {
    int row = dt * 16 + lr;
    int gidx = cb * 4 + g0;
    int g = (gidx & 24) | ((gidx ^ row) & 7);
    bf16x8 bV = *(const bf16x8*)(sKb + row * 512 + g * 16);
#pragma unroll
    for (int mt = 0; mt < 2; ++mt) {
      f32x4 z = {};
      f32x4 o = mfma16x16x32(aP[mt], bV, z);
#pragma unroll
      for (int r = 0; r < 4; ++r) {
        int m = m0 + rb + mt * 16 + g0 * 4 + r;
        int d = h * 128 + dt * 16 + lr;
        OUT1[(size_t)m * 1024 + d] = (bf16_t)o[r];
      }
    }
  }
}

// ---------------------------------------------------------------- launch
extern "C" void kernel_launch(void* const* d_in, const int* in_sizes, int n_in,
                              void* d_out, int out_size, void* d_ws, size_t ws_size,
                              hipStream_t stream) {
  const float* x     = (const float*)d_in[0];
  const float* w_qkv = (const float*)d_in[1];
  const float* w_out = (const float*)d_in[2];
  const float* b_out = (const float*)d_in[3];
  const float* proj  = (const float*)d_in[4];
  float* out = (float*)d_out;

  char* ws = (char*)d_ws;
  // layout: xbf [0,32M) | B1t2 [32M,36M) | Wv [36M,38M) | W3t [38M,40M) | VtG [40M,72M) | OUT1 [72M,104M)
  bf16_t* xbf  = (bf16_t*)(ws);
  bf16_t* B1t2 = (bf16_t*)(ws + 33554432);
  bf16_t* Wv   = (bf16_t*)(ws + 37748736);
  bf16_t* W3t  = (bf16_t*)(ws + 39845888);
  bf16_t* VtG  = (bf16_t*)(ws + 41943040);
  bf16_t* OUT1 = (bf16_t*)(ws + 75497472);

  (void)in_sizes; (void)n_in; (void)out_size; (void)ws_size;

  cvt_bf16<<<1024, 256, 0, stream>>>(x, xbf, 16777216);
  cvt_bf16<<<256, 256, 0, stream>>>(w_out, W3t, 1048576);
  cvt_bf16<<<256, 256, 0, stream>>>(w_qkv + (size_t)2048 * 1024, Wv, 1048576);
  fuse_w<<<256, 256, 0, stream>>>(w_qkv, proj, B1t2);
  // Vt GEMM (operands swapped so Vt[d][m] writes row-major): Vt = Wv @ xbf^T
  gemm256<3><<<256, 512, 0, stream>>>(Wv, xbf, (void*)VtG, nullptr, 16384, 1024, 64);
  // fused: [qp|kp] GEMM + block attention -> OUT1[m][1024]
  gemm_fused<<<512, 512, 0, stream>>>(xbf, B1t2, VtG, OUT1);
  // stage 3: out = OUT1 @ w_out^T + b_out (f32)
  gemm256<2><<<256, 512, 0, stream>>>(OUT1, W3t, (void*)out, b_out, 1024, 1024, 4);
}

// Round 5
// 234.958 us; speedup vs baseline: 1.3283x; 1.0166x over previous
//
#include <hip/hip_runtime.h>
#include <hip/hip_bf16.h>
#include <stdint.h>
#include <stddef.h>

typedef __bf16 bf16_t;
typedef __bf16 bf16x8 __attribute__((ext_vector_type(8)));
typedef __bf16 bf16x4 __attribute__((ext_vector_type(4)));
typedef float  f32x4  __attribute__((ext_vector_type(4)));

static __device__ __forceinline__ f32x4 mfma16x16x32(bf16x8 a, bf16x8 b, f32x4 c) {
  return __builtin_amdgcn_mfma_f32_16x16x32_bf16(a, b, c, 0, 0, 0);
}

static __device__ __forceinline__ void gld_lds16(const void* g, void* l) {
  __builtin_amdgcn_global_load_lds(
      (const __attribute__((address_space(1))) unsigned int*)g,
      (__attribute__((address_space(3))) unsigned int*)l, 16, 0, 0);
}

#define BARW()   __builtin_amdgcn_s_barrier()
#define SCHED0() __builtin_amdgcn_sched_barrier(0)
#define LGKM0()  asm volatile("s_waitcnt lgkmcnt(0)" ::: "memory")
#define LGKMN(n) asm volatile("s_waitcnt lgkmcnt(" #n ")" ::: "memory")
#define VMCNT(n) asm volatile("s_waitcnt vmcnt(" #n ")" ::: "memory")
#define PRIO(p)  __builtin_amdgcn_s_setprio(p)

// ---------------------------------------------------------------- cvt f32->bf16 (x)
__global__ __launch_bounds__(256) void cvt_bf16(const float* __restrict__ in,
                                                bf16_t* __restrict__ out, int n) {
  int stride = gridDim.x * blockDim.x;
  for (int i = blockIdx.x * blockDim.x + threadIdx.x; i * 4 < n; i += stride) {
    float4 v = *(const float4*)(in + (size_t)i * 4);
    bf16x4 o;
    o[0] = (bf16_t)v.x; o[1] = (bf16_t)v.y; o[2] = (bf16_t)v.z; o[3] = (bf16_t)v.w;
    *(bf16x4*)(out + (size_t)i * 4) = o;
  }
}

// ---------------------------------------------------------------- merged prep:
// blocks [0,256): fuse_w ; [256,512): cvt w_out -> W3t ; [512,768): cvt Wv slice -> Wv
__global__ __launch_bounds__(256) void prep(const float* __restrict__ wqkv,
                                            const float* __restrict__ proj,
                                            const float* __restrict__ wout,
                                            bf16_t* __restrict__ B1t2,
                                            bf16_t* __restrict__ Wv,
                                            bf16_t* __restrict__ W3t) {
  const int b = blockIdx.x;
  const int tid = threadIdx.x;
  if (b >= 256) {
    const float* src = (b < 512) ? wout : (wqkv + (size_t)2048 * 1024);
    bf16_t* dst = (b < 512) ? W3t : Wv;
    size_t off = ((size_t)((b & 255)) * 4096) + tid * 16;
#pragma unroll
    for (int it = 0; it < 4; ++it) {
      float4 v = *(const float4*)(src + off + it * 4);
      bf16x4 o;
      o[0] = (bf16_t)v.x; o[1] = (bf16_t)v.y; o[2] = (bf16_t)v.z; o[3] = (bf16_t)v.w;
      *(bf16x4*)(dst + off + it * 4) = o;
    }
    return;
  }
  // fuse_w: B1t2[h*256 + qk*128 + f][k] = sum_c wqkv[(qk*1024+h*128+c)][k] * proj[h][c][f]
  const int combo  = b >> 4;
  const int kt     = b & 15;
  const int qk     = combo >> 3;
  const int h      = combo & 7;
  const int klocal = tid & 63;
  const int fg     = tid >> 6;
  const int k      = kt * 64 + klocal;

  const float* wbase = wqkv + ((size_t)(qk * 1024 + h * 128)) * 1024 + k;
  const float* pbase = proj + (size_t)h * 16384 + fg * 32;

  float acc[32];
#pragma unroll
  for (int i = 0; i < 32; ++i) acc[i] = 0.f;

  for (int c = 0; c < 128; ++c) {
    float a = wbase[(size_t)c * 1024];
    const float4* p = (const float4*)(pbase + (size_t)c * 128);
#pragma unroll
    for (int i = 0; i < 8; ++i) {
      float4 pv = p[i];
      acc[i * 4 + 0] += a * pv.x;
      acc[i * 4 + 1] += a * pv.y;
      acc[i * 4 + 2] += a * pv.z;
      acc[i * 4 + 3] += a * pv.w;
    }
  }
  bf16_t* obase = B1t2 + ((size_t)(h * 256 + qk * 128 + fg * 32)) * 1024 + k;
#pragma unroll
  for (int i = 0; i < 32; ++i) obase[(size_t)i * 1024] = (bf16_t)acc[i];
}

// ================================================================ shared main-loop macros
#define GEMM_MAINLOOP_DECLS()                                                  \
  const int tid  = threadIdx.x;                                                \
  const int lane = tid & 63;                                                   \
  const int wid  = tid >> 6;                                                   \
  const int wm   = wid >> 2;                                                   \
  const int wn   = wid & 3;                                                    \
  const int lr   = lane & 15;                                                  \
  const int g0   = lane >> 4;                                                  \
  int srow[2], sgl[2];                                                         \
  _Pragma("unroll")                                                            \
  for (int l = 0; l < 2; ++l) {                                                \
    int idx = l * 512 + tid;                                                   \
    srow[l] = idx >> 3;                                                        \
    sgl[l]  = (idx & 7) ^ (srow[l] & 7);                                       \
  }

// arr must be a 2D slice: sA[buf] / sB[buf]
#define STAGE_T(arr, base, half, kt, K_)                                       \
  {                                                                            \
    const bf16_t* s_ = (base) + (size_t)((half) * 128) * (K_) + (kt) * 64;     \
    bf16_t* d_ = &(arr)[half][0];                                              \
    _Pragma("unroll")                                                          \
    for (int l_ = 0; l_ < 2; ++l_)                                             \
      gld_lds16(s_ + (size_t)srow[l_] * (K_) + sgl[l_] * 8,                    \
                d_ + (l_ * 512 + tid) * 8);                                    \
  }

#define RD_A(buf, qm)                                                          \
  _Pragma("unroll")                                                            \
  for (int t_ = 0; t_ < 4; ++t_) {                                             \
    int r_ = (qm) * 64 + t_ * 16 + lr;                                         \
    _Pragma("unroll")                                                          \
    for (int kh_ = 0; kh_ < 2; ++kh_) {                                        \
      int gl_ = (g0 + kh_ * 4) ^ (r_ & 7);                                     \
      a[t_][kh_] = *(const bf16x8*)(&sA[buf][wm][r_ * 64 + gl_ * 8]);          \
    }                                                                          \
  }
#define RD_B(buf, qn, breg)                                                    \
  _Pragma("unroll")                                                            \
  for (int u_ = 0; u_ < 2; ++u_) {                                             \
    int r_ = (wn & 1) * 64 + (qn) * 32 + u_ * 16 + lr;                         \
    _Pragma("unroll")                                                          \
    for (int kh_ = 0; kh_ < 2; ++kh_) {                                        \
      int gl_ = (g0 + kh_ * 4) ^ (r_ & 7);                                     \
      breg[u_][kh_] = *(const bf16x8*)(&sB[buf][wn >> 1][r_ * 64 + gl_ * 8]);  \
    }                                                                          \
  }
#define MMA(qm, qn, breg)                                                      \
  _Pragma("unroll")                                                            \
  for (int mi_ = 0; mi_ < 4; ++mi_)                                            \
    _Pragma("unroll")                                                          \
    for (int nj_ = 0; nj_ < 2; ++nj_)                                          \
      _Pragma("unroll")                                                        \
      for (int kh_ = 0; kh_ < 2; ++kh_)                                        \
        acc[(qm) * 4 + mi_][(qn) * 2 + nj_] =                                  \
            mfma16x16x32(a[mi_][kh_], breg[nj_][kh_],                          \
                         acc[(qm) * 4 + mi_][(qn) * 2 + nj_]);

#define GEMM_MAINLOOP_BODY(Abase, Bbase, K_, NT_)                              \
  f32x4 acc[8][4] = {};                                                        \
  bf16x8 a[4][2], b0[2][2], b1[2][2];                                          \
  STAGE_T(sA[0], Abase, 0, 0, K_); STAGE_T(sA[0], Abase, 1, 0, K_);            \
  STAGE_T(sB[0], Bbase, 0, 0, K_); STAGE_T(sB[0], Bbase, 1, 0, K_);            \
  STAGE_T(sA[1], Abase, 0, 1, K_); STAGE_T(sA[1], Abase, 1, 1, K_);            \
  STAGE_T(sB[1], Bbase, 0, 1, K_); STAGE_T(sB[1], Bbase, 1, 1, K_);            \
  VMCNT(8);                                                                    \
  BARW();                                                                      \
  _Pragma("unroll 2")                                                          \
  for (int j = 0; j < (NT_); ++j) {                                            \
    const int cur = j & 1;                                                     \
    const bool pf = (j + 2) < (NT_);                                           \
    RD_A(cur, 0);                                                              \
    RD_B(cur, 0, b0);                                                          \
    SCHED0(); LGKMN(8); BARW(); LGKM0(); SCHED0();                             \
    PRIO(1); MMA(0, 0, b0); PRIO(0);                                           \
    SCHED0(); BARW();                                                          \
    RD_B(cur, 1, b1);                                                          \
    SCHED0(); BARW(); LGKM0(); SCHED0();                                       \
    PRIO(1); MMA(0, 1, b1); PRIO(0);                                           \
    SCHED0(); BARW();                                                          \
    RD_A(cur, 1);                                                              \
    if (pf) { STAGE_T(sB[cur], Bbase, 0, j + 2, K_); STAGE_T(sB[cur], Bbase, 1, j + 2, K_); } \
    SCHED0(); LGKMN(4); BARW(); LGKM0(); SCHED0();                             \
    PRIO(1); MMA(1, 1, b1); PRIO(0);                                           \
    SCHED0(); BARW();                                                          \
    if (pf) { STAGE_T(sA[cur], Abase, 0, j + 2, K_); STAGE_T(sA[cur], Abase, 1, j + 2, K_); } \
    SCHED0(); BARW();                                                          \
    PRIO(1); MMA(1, 0, b0); PRIO(0);                                           \
    if (pf) { VMCNT(8); } else { VMCNT(0); }                                   \
    SCHED0(); BARW();                                                          \
  }

// ---------------------------------------------------------------- 256^2 8-phase GEMM
// EPI 2: f32 out + bias    EPI 3: bf16 out row-major (no bias)
template <int EPI>
__global__ __launch_bounds__(512, 2) void gemm256(const bf16_t* __restrict__ A,
                                                  const bf16_t* __restrict__ Bt,
                                                  void* __restrict__ Cout,
                                                  const float* __restrict__ bias,
                                                  int N, int K, int NB) {
  __shared__ __align__(16) bf16_t sA[2][2][8192];
  __shared__ __align__(16) bf16_t sB[2][2][8192];
  GEMM_MAINLOOP_DECLS();

  const int nwg = gridDim.x;
  const int cpx = nwg >> 3;
  const int bid = blockIdx.x;
  const int swz = (bid & 7) * cpx + (bid >> 3);
  const int m0 = (swz / NB) * 256;
  const int n0 = (swz % NB) * 256;
  const int NT = K >> 6;

  const bf16_t* Abase = A  + (size_t)m0 * K;
  const bf16_t* Bbase = Bt + (size_t)n0 * K;

  GEMM_MAINLOOP_BODY(Abase, Bbase, K, NT);

#pragma unroll
  for (int i = 0; i < 8; ++i) {
#pragma unroll
    for (int jn = 0; jn < 4; ++jn) {
      const int n = n0 + wn * 64 + jn * 16 + lr;
#pragma unroll
      for (int r = 0; r < 4; ++r) {
        const int m = m0 + wm * 128 + i * 16 + g0 * 4 + r;
        float v = acc[i][jn][r];
        if constexpr (EPI == 2) {
          ((float*)Cout)[(size_t)m * N + n] = v + bias[n];
        } else {
          ((bf16_t*)Cout)[(size_t)m * N + n] = (bf16_t)v;
        }
      }
    }
  }
}

// ---------------------------------------------------------------- fused qp/kp GEMM + block attention
// Block (mtile, h): [qp|kp] (256 x 256) for head h; per 32-row c-block:
// S = qp kp^T (32x32), z = rowsum(S), out = (S/z) v  -> OUT1[m][h*128+d]
__global__ __launch_bounds__(512, 2) void gemm_fused(const bf16_t* __restrict__ A,
                                                     const bf16_t* __restrict__ Bt,
                                                     const bf16_t* __restrict__ VtG,
                                                     bf16_t* __restrict__ OUT1) {
  __shared__ __align__(16) bf16_t sA[2][2][8192];
  __shared__ __align__(16) bf16_t sB[2][2][8192];
  GEMM_MAINLOOP_DECLS();

  const int nwg = gridDim.x;          // 512
  const int cpx = nwg >> 3;
  const int bid = blockIdx.x;
  const int swz = (bid & 7) * cpx + (bid >> 3);
  const int m0 = (swz >> 3) * 256;
  const int h  = swz & 7;
  const int K  = 1024;
  const int NT = 16;

  const bf16_t* Abase = A  + (size_t)m0 * K;
  const bf16_t* Bbase = Bt + (size_t)(h * 256) * K;

  GEMM_MAINLOOP_BODY(Abase, Bbase, K, NT);

  // ---------------- fused attention epilogue ----------------
  char* sQb = (char*)(&sA[0][0][0]);   // Qp: 256 rows x 256B (swizzled granules)
  char* sKb = (char*)(&sB[0][0][0]);   // Kp: same; later reused for Vt (128 x 512B)

  // ep1: elu+1, cvt, scatter acc -> LDS
  {
    char* dbase = (wn < 2) ? sQb : sKb;
#pragma unroll
    for (int i = 0; i < 8; ++i)
#pragma unroll
      for (int jn = 0; jn < 4; ++jn)
#pragma unroll
        for (int r = 0; r < 4; ++r) {
          int row = wm * 128 + i * 16 + g0 * 4 + r;
          int col = (wn & 1) * 64 + jn * 16 + lr;     // 0..127 within Q or K
          float v = acc[i][jn][r];
          v = v > 0.f ? v + 1.f : __expf(v);
          int gq = col >> 3;
          int g  = (gq & 8) | ((gq ^ row) & 7);
          *(bf16_t*)(dbase + row * 256 + g * 16 + (col & 7) * 2) = (bf16_t)v;
        }
  }
  LGKM0();
  BARW();

  // ep2a: read ALL S-operand fragments up-front (T14 prep)
  const int cb = wm * 4 + wn;          // 0..7, one wave per c-block
  const int rb = cb * 32;
  bf16x8 aS[4][2], bS[4][2];
#pragma unroll
  for (int kh = 0; kh < 4; ++kh) {
#pragma unroll
    for (int t = 0; t < 2; ++t) {
      int row = rb + t * 16 + lr;
      int gq = kh * 4 + g0;
      int g  = (gq & 8) | ((gq ^ row) & 7);
      aS[kh][t] = *(const bf16x8*)(sQb + row * 256 + g * 16);
      bS[kh][t] = *(const bf16x8*)(sKb + row * 256 + g * 16);
    }
  }
  SCHED0(); LGKM0(); BARW();   // all Qp/Kp reads complete chip-wide; LDS reusable

  // ep2b: issue Vt stage into sKb NOW (latency hides under S-MFMA + rowsum)
  {
#pragma unroll
    for (int l = 0; l < 8; ++l) {
      int gd = l * 512 + tid;
      int row = gd >> 5, gcol = gd & 31;
      const bf16_t* src = VtG + (size_t)(h * 128 + row) * 16384 + m0 +
                          ((gcol ^ (row & 7)) * 8);
      gld_lds16(src, sKb + gd * 16);
    }
  }
  SCHED0();

  // ep2c: S = qp kp^T (register-only)
  f32x4 sacc[2][2] = {};
#pragma unroll
  for (int kh = 0; kh < 4; ++kh)
#pragma unroll
    for (int mt = 0; mt < 2; ++mt)
#pragma unroll
      for (int nt = 0; nt < 2; ++nt)
        sacc[mt][nt] = mfma16x16x32(aS[kh][mt], bS[kh][nt], sacc[mt][nt]);

  // rowsum over j -> zinv
  float zin[2][4];
#pragma unroll
  for (int mt = 0; mt < 2; ++mt)
#pragma unroll
    for (int r = 0; r < 4; ++r) {
      float s = sacc[mt][0][r] + sacc[mt][1][r];
      s += __shfl_xor(s, 1); s += __shfl_xor(s, 2);
      s += __shfl_xor(s, 4); s += __shfl_xor(s, 8);
      zin[mt][r] = 1.0f / (s + 1e-8f);
    }

  // ep3: P -> Pl (sQb region, 8 x [32 x 80B])
  char* Pl = sQb;
#pragma unroll
  for (int mt = 0; mt < 2; ++mt)
#pragma unroll
    for (int nt = 0; nt < 2; ++nt)
#pragma unroll
      for (int r = 0; r < 4; ++r) {
        int i = mt * 16 + g0 * 4 + r;
        int jj = nt * 16 + lr;
        *(bf16_t*)(Pl + cb * 2560 + i * 80 + jj * 2) =
            (bf16_t)(sacc[mt][nt][r] * zin[mt][r]);
      }
  LGKM0();
  VMCNT(0);
  BARW();

  // ep4: out = P . v  (one MFMA per (mt,dt)), write OUT1
  bf16x8 aP[2];
#pragma unroll
  for (int mt = 0; mt < 2; ++mt)
    aP[mt] = *(const bf16x8*)(Pl + cb * 2560 + (mt * 16 + lr) * 80 + g0 * 16);
#pragma unroll
  for (int dt = 0; dt < 8; ++dt) {
    int row = dt * 16 + lr;
    int gidx = cb * 4 + g0;
    int g = (gidx & 24) | ((gidx ^ row) & 7);
    bf16x8 bV = *(const bf16x8*)(sKb + row * 512 + g * 16);
#pragma unroll
    for (int mt = 0; mt < 2; ++mt) {
      f32x4 z = {};
      f32x4 o = mfma16x16x32(aP[mt], bV, z);
#pragma unroll
      for (int r = 0; r < 4; ++r) {
        int m = m0 + rb + mt * 16 + g0 * 4 + r;
        int d = h * 128 + dt * 16 + lr;
        OUT1[(size_t)m * 1024 + d] = (bf16_t)o[r];
      }
    }
  }
}

// ---------------------------------------------------------------- launch
extern "C" void kernel_launch(void* const* d_in, const int* in_sizes, int n_in,
                              void* d_out, int out_size, void* d_ws, size_t ws_size,
                              hipStream_t stream) {
  const float* x     = (const float*)d_in[0];
  const float* w_qkv = (const float*)d_in[1];
  const float* w_out = (const float*)d_in[2];
  const float* b_out = (const float*)d_in[3];
  const float* proj  = (const float*)d_in[4];
  float* out = (float*)d_out;

  char* ws = (char*)d_ws;
  // layout: xbf [0,32M) | B1t2 [32M,36M) | Wv [36M,38M) | W3t [38M,40M) | VtG [40M,72M) | OUT1 [72M,104M)
  bf16_t* xbf  = (bf16_t*)(ws);
  bf16_t* B1t2 = (bf16_t*)(ws + 33554432);
  bf16_t* Wv   = (bf16_t*)(ws + 37748736);
  bf16_t* W3t  = (bf16_t*)(ws + 39845888);
  bf16_t* VtG  = (bf16_t*)(ws + 41943040);
  bf16_t* OUT1 = (bf16_t*)(ws + 75497472);

  (void)in_sizes; (void)n_in; (void)out_size; (void)ws_size;

  prep<<<768, 256, 0, stream>>>(w_qkv, proj, w_out, B1t2, Wv, W3t);
  cvt_bf16<<<1024, 256, 0, stream>>>(x, xbf, 16777216);
  // Vt GEMM (operands swapped so Vt[d][m] writes row-major): Vt = Wv @ xbf^T
  gemm256<3><<<256, 512, 0, stream>>>(Wv, xbf, (void*)VtG, nullptr, 16384, 1024, 64);
  // fused: [qp|kp] GEMM + block attention -> OUT1[m][1024]
  gemm_fused<<<512, 512, 0, stream>>>(xbf, B1t2, VtG, OUT1);
  // stage 3: out = OUT1 @ w_out^T + b_out (f32)
  gemm256<2><<<256, 512, 0, stream>>>(OUT1, W3t, (void*)out, b_out, 1024, 1024, 4);
}

// Round 6
// 227.673 us; speedup vs baseline: 1.3708x; 1.0320x over previous
//
#include <hip/hip_runtime.h>
#include <hip/hip_bf16.h>
#include <stdint.h>
#include <stddef.h>

typedef __bf16 bf16_t;
typedef __bf16 bf16x8 __attribute__((ext_vector_type(8)));
typedef __bf16 bf16x4 __attribute__((ext_vector_type(4)));
typedef float  f32x4  __attribute__((ext_vector_type(4)));

static __device__ __forceinline__ f32x4 mfma16x16x32(bf16x8 a, bf16x8 b, f32x4 c) {
  return __builtin_amdgcn_mfma_f32_16x16x32_bf16(a, b, c, 0, 0, 0);
}

static __device__ __forceinline__ void gld_lds16(const void* g, void* l) {
  __builtin_amdgcn_global_load_lds(
      (const __attribute__((address_space(1))) unsigned int*)g,
      (__attribute__((address_space(3))) unsigned int*)l, 16, 0, 0);
}

#define BARW()   __builtin_amdgcn_s_barrier()
#define SCHED0() __builtin_amdgcn_sched_barrier(0)
#define LGKM0()  asm volatile("s_waitcnt lgkmcnt(0)" ::: "memory")
#define VMCNT(n) asm volatile("s_waitcnt vmcnt(" #n ")" ::: "memory")
#define PRIO(p)  __builtin_amdgcn_s_setprio(p)

// ---------------------------------------------------------------- merged prep:
// [0,256): fuse_w ; [256,512): cvt w_out ; [512,768): cvt Wv ; [768,1792): cvt x
__global__ __launch_bounds__(256) void prep(const float* __restrict__ wqkv,
                                            const float* __restrict__ proj,
                                            const float* __restrict__ wout,
                                            const float* __restrict__ x,
                                            bf16_t* __restrict__ B1t2,
                                            bf16_t* __restrict__ Wv,
                                            bf16_t* __restrict__ W3t,
                                            bf16_t* __restrict__ xbf) {
  const int b = blockIdx.x;
  const int tid = threadIdx.x;
  if (b >= 768) {
    // cvt x: 16777216 elems = 4194304 float4; 1024 blocks * 256 thr -> 16 iters
    for (int i = (b - 768) * 256 + tid; i < 4194304; i += 262144) {
      float4 v = *(const float4*)(x + (size_t)i * 4);
      bf16x4 o;
      o[0] = (bf16_t)v.x; o[1] = (bf16_t)v.y; o[2] = (bf16_t)v.z; o[3] = (bf16_t)v.w;
      *(bf16x4*)(xbf + (size_t)i * 4) = o;
    }
    return;
  }
  if (b >= 256) {
    const float* src = (b < 512) ? wout : (wqkv + (size_t)2048 * 1024);
    bf16_t* dst = (b < 512) ? W3t : Wv;
    size_t off = ((size_t)((b & 255)) * 4096) + tid * 16;
#pragma unroll
    for (int it = 0; it < 4; ++it) {
      float4 v = *(const float4*)(src + off + it * 4);
      bf16x4 o;
      o[0] = (bf16_t)v.x; o[1] = (bf16_t)v.y; o[2] = (bf16_t)v.z; o[3] = (bf16_t)v.w;
      *(bf16x4*)(dst + off + it * 4) = o;
    }
    return;
  }
  // fuse_w: B1t2[h*256 + qk*128 + f][k] = sum_c wqkv[(qk*1024+h*128+c)][k] * proj[h][c][f]
  const int combo  = b >> 4;
  const int kt     = b & 15;
  const int qk     = combo >> 3;
  const int h      = combo & 7;
  const int klocal = tid & 63;
  const int fg     = tid >> 6;
  const int k      = kt * 64 + klocal;

  const float* wbase = wqkv + ((size_t)(qk * 1024 + h * 128)) * 1024 + k;
  const float* pbase = proj + (size_t)h * 16384 + fg * 32;

  float acc[32];
#pragma unroll
  for (int i = 0; i < 32; ++i) acc[i] = 0.f;

  for (int c = 0; c < 128; ++c) {
    float a = wbase[(size_t)c * 1024];
    const float4* p = (const float4*)(pbase + (size_t)c * 128);
#pragma unroll
    for (int i = 0; i < 8; ++i) {
      float4 pv = p[i];
      acc[i * 4 + 0] += a * pv.x;
      acc[i * 4 + 1] += a * pv.y;
      acc[i * 4 + 2] += a * pv.z;
      acc[i * 4 + 3] += a * pv.w;
    }
  }
  bf16_t* obase = B1t2 + ((size_t)(h * 256 + qk * 128 + fg * 32)) * 1024 + k;
#pragma unroll
  for (int i = 0; i < 32; ++i) obase[(size_t)i * 1024] = (bf16_t)acc[i];
}

// ================================================================ shared main-loop macros
#define GEMM_MAINLOOP_DECLS()                                                  \
  const int tid  = threadIdx.x;                                                \
  const int lane = tid & 63;                                                   \
  const int wid  = tid >> 6;                                                   \
  const int wm   = wid >> 2;                                                   \
  const int wn   = wid & 3;                                                    \
  const int lr   = lane & 15;                                                  \
  const int g0   = lane >> 4;                                                  \
  int srow[2], sgl[2];                                                         \
  _Pragma("unroll")                                                            \
  for (int l = 0; l < 2; ++l) {                                                \
    int idx = l * 512 + tid;                                                   \
    srow[l] = idx >> 3;                                                        \
    sgl[l]  = (idx & 7) ^ (srow[l] & 7);                                       \
  }

// arr must be a 2D slice: sA[buf] / sB[buf]
#define STAGE_T(arr, base, half, kt, K_)                                       \
  {                                                                            \
    const bf16_t* s_ = (base) + (size_t)((half) * 128) * (K_) + (kt) * 64;     \
    bf16_t* d_ = &(arr)[half][0];                                              \
    _Pragma("unroll")                                                          \
    for (int l_ = 0; l_ < 2; ++l_)                                             \
      gld_lds16(s_ + (size_t)srow[l_] * (K_) + sgl[l_] * 8,                    \
                d_ + (l_ * 512 + tid) * 8);                                    \
  }

#define RD_A(buf, qm)                                                          \
  _Pragma("unroll")                                                            \
  for (int t_ = 0; t_ < 4; ++t_) {                                             \
    int r_ = (qm) * 64 + t_ * 16 + lr;                                         \
    _Pragma("unroll")                                                          \
    for (int kh_ = 0; kh_ < 2; ++kh_) {                                        \
      int gl_ = (g0 + kh_ * 4) ^ (r_ & 7);                                     \
      a[t_][kh_] = *(const bf16x8*)(&sA[buf][wm][r_ * 64 + gl_ * 8]);          \
    }                                                                          \
  }
#define RD_B(buf, qn, breg)                                                    \
  _Pragma("unroll")                                                            \
  for (int u_ = 0; u_ < 2; ++u_) {                                             \
    int r_ = (wn & 1) * 64 + (qn) * 32 + u_ * 16 + lr;                         \
    _Pragma("unroll")                                                          \
    for (int kh_ = 0; kh_ < 2; ++kh_) {                                        \
      int gl_ = (g0 + kh_ * 4) ^ (r_ & 7);                                     \
      breg[u_][kh_] = *(const bf16x8*)(&sB[buf][wn >> 1][r_ * 64 + gl_ * 8]);  \
    }                                                                          \
  }
#define MMA(qm, qn, breg)                                                      \
  _Pragma("unroll")                                                            \
  for (int mi_ = 0; mi_ < 4; ++mi_)                                            \
    _Pragma("unroll")                                                          \
    for (int nj_ = 0; nj_ < 2; ++nj_)                                          \
      _Pragma("unroll")                                                        \
      for (int kh_ = 0; kh_ < 2; ++kh_)                                        \
        acc[(qm) * 4 + mi_][(qn) * 2 + nj_] =                                  \
            mfma16x16x32(a[mi_][kh_], breg[nj_][kh_],                          \
                         acc[(qm) * 4 + mi_][(qn) * 2 + nj_]);

// m201-faithful schedule: 2 global_load_lds per phase, vmcnt(4) once per K-tile.
// tile j phases stage: P1: B-h1(j+1)->nxt, P2: A-h1(j+1)->nxt (those regions last
// read at tile j-1), P3: B-h0(j+2)->cur (B reads of tile j end at P2),
// P4: A-h0(j+2)->cur (A reads end at P3). vmcnt(4) at P4 covers tile j+1 fully.
#define GEMM_MAINLOOP_BODY(Abase, Bbase, K_, NT_)                              \
  f32x4 acc[8][4] = {};                                                        \
  bf16x8 a[4][2], b0[2][2], b1[2][2];                                          \
  STAGE_T(sB[0], Bbase, 0, 0, K_); STAGE_T(sA[0], Abase, 0, 0, K_);            \
  STAGE_T(sB[0], Bbase, 1, 0, K_); STAGE_T(sA[0], Abase, 1, 0, K_);            \
  STAGE_T(sB[1], Bbase, 0, 1, K_); STAGE_T(sA[1], Abase, 0, 1, K_);            \
  VMCNT(4);                                                                    \
  BARW();                                                                      \
  _Pragma("unroll 2")                                                          \
  for (int j = 0; j < (NT_); ++j) {                                            \
    const int cur = j & 1;                                                     \
    const int nxt = cur ^ 1;                                                   \
    /* P1: reads A(q0)+B(q0); stage B-h1(j+1); MFMA (0,0) */                   \
    RD_A(cur, 0);                                                              \
    RD_B(cur, 0, b0);                                                          \
    if (j + 1 < (NT_)) { STAGE_T(sB[nxt], Bbase, 1, j + 1, K_); }              \
    SCHED0(); BARW(); LGKM0(); SCHED0();                                       \
    PRIO(1); MMA(0, 0, b0); PRIO(0);                                           \
    SCHED0(); BARW();                                                          \
    /* P2: reads B(q1); stage A-h1(j+1); MFMA (0,1) */                         \
    RD_B(cur, 1, b1);                                                          \
    if (j + 1 < (NT_)) { STAGE_T(sA[nxt], Abase, 1, j + 1, K_); }              \
    SCHED0(); BARW(); LGKM0(); SCHED0();                                       \
    PRIO(1); MMA(0, 1, b1); PRIO(0);                                           \
    SCHED0(); BARW();                                                          \
    /* P3: reads A(q1); stage B-h0(j+2); MFMA (1,1) */                         \
    RD_A(cur, 1);                                                              \
    if (j + 2 < (NT_)) { STAGE_T(sB[cur], Bbase, 0, j + 2, K_); }              \
    SCHED0(); BARW(); LGKM0(); SCHED0();                                       \
    PRIO(1); MMA(1, 1, b1); PRIO(0);                                           \
    SCHED0(); BARW();                                                          \
    /* P4: stage A-h0(j+2); MFMA (1,0); counted vmcnt */                       \
    if (j + 2 < (NT_)) { STAGE_T(sA[cur], Abase, 0, j + 2, K_); }              \
    SCHED0(); BARW();                                                          \
    PRIO(1); MMA(1, 0, b0); PRIO(0);                                           \
    if (j + 2 < (NT_)) { VMCNT(4); } else { VMCNT(0); }                        \
    SCHED0(); BARW();                                                          \
  }

// ---------------------------------------------------------------- 256^2 8-phase GEMM
// EPI 2: f32 out + bias    EPI 3: bf16 out row-major (no bias)
template <int EPI>
__global__ __launch_bounds__(512, 2) void gemm256(const bf16_t* __restrict__ A,
                                                  const bf16_t* __restrict__ Bt,
                                                  void* __restrict__ Cout,
                                                  const float* __restrict__ bias,
                                                  int N, int K, int NB) {
  __shared__ __align__(16) bf16_t sA[2][2][8192];
  __shared__ __align__(16) bf16_t sB[2][2][8192];
  GEMM_MAINLOOP_DECLS();

  const int nwg = gridDim.x;
  const int cpx = nwg >> 3;
  const int bid = blockIdx.x;
  const int swz = (bid & 7) * cpx + (bid >> 3);
  const int m0 = (swz / NB) * 256;
  const int n0 = (swz % NB) * 256;
  const int NT = K >> 6;

  const bf16_t* Abase = A  + (size_t)m0 * K;
  const bf16_t* Bbase = Bt + (size_t)n0 * K;

  GEMM_MAINLOOP_BODY(Abase, Bbase, K, NT);

#pragma unroll
  for (int i = 0; i < 8; ++i) {
#pragma unroll
    for (int jn = 0; jn < 4; ++jn) {
      const int n = n0 + wn * 64 + jn * 16 + lr;
#pragma unroll
      for (int r = 0; r < 4; ++r) {
        const int m = m0 + wm * 128 + i * 16 + g0 * 4 + r;
        float v = acc[i][jn][r];
        if constexpr (EPI == 2) {
          ((float*)Cout)[(size_t)m * N + n] = v + bias[n];
        } else {
          ((bf16_t*)Cout)[(size_t)m * N + n] = (bf16_t)v;
        }
      }
    }
  }
}

// ---------------------------------------------------------------- fused qp/kp GEMM + block attention
__global__ __launch_bounds__(512, 2) void gemm_fused(const bf16_t* __restrict__ A,
                                                     const bf16_t* __restrict__ Bt,
                                                     const bf16_t* __restrict__ VtG,
                                                     bf16_t* __restrict__ OUT1) {
  __shared__ __align__(16) bf16_t sA[2][2][8192];
  __shared__ __align__(16) bf16_t sB[2][2][8192];
  GEMM_MAINLOOP_DECLS();

  const int nwg = gridDim.x;          // 512
  const int cpx = nwg >> 3;
  const int bid = blockIdx.x;
  const int swz = (bid & 7) * cpx + (bid >> 3);
  const int m0 = (swz >> 3) * 256;
  const int h  = swz & 7;
  const int K  = 1024;
  const int NT = 16;

  const bf16_t* Abase = A  + (size_t)m0 * K;
  const bf16_t* Bbase = Bt + (size_t)(h * 256) * K;

  GEMM_MAINLOOP_BODY(Abase, Bbase, K, NT);

  // ---------------- fused attention epilogue ----------------
  char* sQb = (char*)(&sA[0][0][0]);   // Qp: 256 rows x 256B (swizzled granules)
  char* sKb = (char*)(&sB[0][0][0]);   // Kp: same; later reused for Vt (128 x 512B)

  // ep1: elu+1, cvt, scatter acc -> LDS
  {
    char* dbase = (wn < 2) ? sQb : sKb;
#pragma unroll
    for (int i = 0; i < 8; ++i)
#pragma unroll
      for (int jn = 0; jn < 4; ++jn)
#pragma unroll
        for (int r = 0; r < 4; ++r) {
          int row = wm * 128 + i * 16 + g0 * 4 + r;
          int col = (wn & 1) * 64 + jn * 16 + lr;     // 0..127 within Q or K
          float v = acc[i][jn][r];
          v = v > 0.f ? v + 1.f : __expf(v);
          int gq = col >> 3;
          int g  = (gq & 8) | ((gq ^ row) & 7);
          *(bf16_t*)(dbase + row * 256 + g * 16 + (col & 7) * 2) = (bf16_t)v;
        }
  }
  LGKM0();
  BARW();

  // ep2a: read ALL S-operand fragments up-front
  const int cb = wm * 4 + wn;          // 0..7, one wave per c-block
  const int rb = cb * 32;
  bf16x8 aS[4][2], bS[4][2];
#pragma unroll
  for (int kh = 0; kh < 4; ++kh) {
#pragma unroll
    for (int t = 0; t < 2; ++t) {
      int row = rb + t * 16 + lr;
      int gq = kh * 4 + g0;
      int g  = (gq & 8) | ((gq ^ row) & 7);
      aS[kh][t] = *(const bf16x8*)(sQb + row * 256 + g * 16);
      bS[kh][t] = *(const bf16x8*)(sKb + row * 256 + g * 16);
    }
  }
  SCHED0(); LGKM0(); BARW();   // all Qp/Kp reads complete; LDS reusable

  // ep2b: issue Vt stage into sKb (latency hides under S-MFMA + rowsum)
  {
#pragma unroll
    for (int l = 0; l < 8; ++l) {
      int gd = l * 512 + tid;
      int row = gd >> 5, gcol = gd & 31;
      const bf16_t* src = VtG + (size_t)(h * 128 + row) * 16384 + m0 +
                          ((gcol ^ (row & 7)) * 8);
      gld_lds16(src, sKb + gd * 16);
    }
  }
  SCHED0();

  // ep2c: S = qp kp^T (register-only)
  f32x4 sacc[2][2] = {};
#pragma unroll
  for (int kh = 0; kh < 4; ++kh)
#pragma unroll
    for (int mt = 0; mt < 2; ++mt)
#pragma unroll
      for (int nt = 0; nt < 2; ++nt)
        sacc[mt][nt] = mfma16x16x32(aS[kh][mt], bS[kh][nt], sacc[mt][nt]);

  // rowsum over j -> zinv
  float zin[2][4];
#pragma unroll
  for (int mt = 0; mt < 2; ++mt)
#pragma unroll
    for (int r = 0; r < 4; ++r) {
      float s = sacc[mt][0][r] + sacc[mt][1][r];
      s += __shfl_xor(s, 1); s += __shfl_xor(s, 2);
      s += __shfl_xor(s, 4); s += __shfl_xor(s, 8);
      zin[mt][r] = 1.0f / (s + 1e-8f);
    }

  // ep3: P -> Pl (sQb region, 8 x [32 x 80B])
  char* Pl = sQb;
#pragma unroll
  for (int mt = 0; mt < 2; ++mt)
#pragma unroll
    for (int nt = 0; nt < 2; ++nt)
#pragma unroll
      for (int r = 0; r < 4; ++r) {
        int i = mt * 16 + g0 * 4 + r;
        int jj = nt * 16 + lr;
        *(bf16_t*)(Pl + cb * 2560 + i * 80 + jj * 2) =
            (bf16_t)(sacc[mt][nt][r] * zin[mt][r]);
      }
  LGKM0();
  VMCNT(0);
  BARW();

  // ep4: out = P . v  (one MFMA per (mt,dt)), write OUT1
  bf16x8 aP[2];
#pragma unroll
  for (int mt = 0; mt < 2; ++mt)
    aP[mt] = *(const bf16x8*)(Pl + cb * 2560 + (mt * 16 + lr) * 80 + g0 * 16);
#pragma unroll
  for (int dt = 0; dt < 8; ++dt) {
    int row = dt * 16 + lr;
    int gidx = cb * 4 + g0;
    int g = (gidx & 24) | ((gidx ^ row) & 7);
    bf16x8 bV = *(const bf16x8*)(sKb + row * 512 + g * 16);
#pragma unroll
    for (int mt = 0; mt < 2; ++mt) {
      f32x4 z = {};
      f32x4 o = mfma16x16x32(aP[mt], bV, z);
#pragma unroll
      for (int r = 0; r < 4; ++r) {
        int m = m0 + rb + mt * 16 + g0 * 4 + r;
        int d = h * 128 + dt * 16 + lr;
        OUT1[(size_t)m * 1024 + d] = (bf16_t)o[r];
      }
    }
  }
}

// ---------------------------------------------------------------- launch
extern "C" void kernel_launch(void* const* d_in, const int* in_sizes, int n_in,
                              void* d_out, int out_size, void* d_ws, size_t ws_size,
                              hipStream_t stream) {
  const float* x     = (const float*)d_in[0];
  const float* w_qkv = (const float*)d_in[1];
  const float* w_out = (const float*)d_in[2];
  const float* b_out = (const float*)d_in[3];
  const float* proj  = (const float*)d_in[4];
  float* out = (float*)d_out;

  char* ws = (char*)d_ws;
  // layout: xbf [0,32M) | B1t2 [32M,36M) | Wv [36M,38M) | W3t [38M,40M) | VtG [40M,72M) | OUT1 [72M,104M)
  bf16_t* xbf  = (bf16_t*)(ws);
  bf16_t* B1t2 = (bf16_t*)(ws + 33554432);
  bf16_t* Wv   = (bf16_t*)(ws + 37748736);
  bf16_t* W3t  = (bf16_t*)(ws + 39845888);
  bf16_t* VtG  = (bf16_t*)(ws + 41943040);
  bf16_t* OUT1 = (bf16_t*)(ws + 75497472);

  (void)in_sizes; (void)n_in; (void)out_size; (void)ws_size;

  prep<<<1792, 256, 0, stream>>>(w_qkv, proj, w_out, x, B1t2, Wv, W3t, xbf);
  // Vt GEMM (operands swapped so Vt[d][m] writes row-major): Vt = Wv @ xbf^T
  gemm256<3><<<256, 512, 0, stream>>>(Wv, xbf, (void*)VtG, nullptr, 16384, 1024, 64);
  // fused: [qp|kp] GEMM + block attention -> OUT1[m][1024]
  gemm_fused<<<512, 512, 0, stream>>>(xbf, B1t2, VtG, OUT1);
  // stage 3: out = OUT1 @ w_out^T + b_out (f32)
  gemm256<2><<<256, 512, 0, stream>>>(OUT1, W3t, (void*)out, b_out, 1024, 1024, 4);
}